// Round 1
// baseline (1570.451 us; speedup 1.0000x reference)
//
#include <hip/hip_runtime.h>

typedef unsigned short ushort_t;

__device__ __forceinline__ float sigf(float x) { return 1.0f / (1.0f + __expf(-x)); }
__device__ __forceinline__ float tanhf_fast(float x) { return 1.0f - 2.0f / (__expf(2.0f * x) + 1.0f); }
__device__ __forceinline__ ushort_t f2bf(float f) {
    unsigned u = __float_as_uint(f);
    unsigned r = (u + 0x7fffu + ((u >> 16) & 1u)) >> 16;
    return (ushort_t)r;
}
__device__ __forceinline__ float dot4(float4 a, float4 b) {
    return a.x * b.x + a.y * b.y + a.z * b.z + a.w * b.w;
}

// ---------------------------------------------------------------------------
// K1/K3: out[n][j] = b1[j] (+ b2[j]) + dot(X[row(n)], W[j])   (K=128)
// 4 tokens per block, blockDim = J (number of output features).
// row(n): toks==null -> n; divv==0 -> toks[n]; else b=n/divv, toks[b*(divv+1)+n%divv]
// ---------------------------------------------------------------------------
__global__ void tok_gemv_kernel(const float* __restrict__ X,
                                const int* __restrict__ toks,
                                int divv,
                                const float* __restrict__ W,
                                const float* __restrict__ b1,
                                const float* __restrict__ b2,
                                float* __restrict__ out,
                                int ntok)
{
    __shared__ __align__(16) float xs[4 * 128];
    int J = blockDim.x;
    int n0 = blockIdx.x * 4;
    for (int i = threadIdx.x; i < 4 * 128; i += J) {
        int tt = i >> 7, k = i & 127;
        int n = n0 + tt;
        if (n >= ntok) n = ntok - 1;
        int row;
        if (!toks) row = n;
        else if (divv == 0) row = toks[n];
        else { int bb = n / divv; int t = n - bb * divv; row = toks[bb * (divv + 1) + t]; }
        xs[i] = X[row * 128 + k];
    }
    __syncthreads();
    int j = threadIdx.x;
    float bias = b1[j] + (b2 ? b2[j] : 0.0f);
    const float4* wr = (const float4*)(W + j * 128);
    const float4* x0 = (const float4*)(xs);
    const float4* x1 = (const float4*)(xs + 128);
    const float4* x2 = (const float4*)(xs + 256);
    const float4* x3 = (const float4*)(xs + 384);
    float a0 = 0.f, a1 = 0.f, a2 = 0.f, a3 = 0.f;
#pragma unroll 8
    for (int k4 = 0; k4 < 32; ++k4) {
        float4 w4 = wr[k4];
        a0 += dot4(w4, x0[k4]);
        a1 += dot4(w4, x1[k4]);
        a2 += dot4(w4, x2[k4]);
        a3 += dot4(w4, x3[k4]);
    }
    float accs[4] = {a0, a1, a2, a3};
#pragma unroll
    for (int tt = 0; tt < 4; ++tt) {
        int n = n0 + tt;
        if (n < ntok) out[n * J + j] = bias + accs[tt];
    }
}

// ---------------------------------------------------------------------------
// K2: encoder LSTM recurrence. One block per batch element, 512 threads.
// gates[j] = gih[b,t,j] + dot(h, Whh[j]);  LSTM pointwise on threads 0..127.
// ---------------------------------------------------------------------------
__global__ void __launch_bounds__(512) enc_rnn_kernel(const float* __restrict__ gih,
                                                      const float* __restrict__ Whh,
                                                      float* __restrict__ enc_out)
{
    int b = blockIdx.x, tid = threadIdx.x;
    __shared__ __align__(16) float h[128];
    __shared__ float gates[512];
    float c = 0.f;
    if (tid < 128) h[tid] = 0.f;
    const float4* wr = (const float4*)(Whh + tid * 128);
    for (int t = 0; t < 50; ++t) {
        __syncthreads();
        float acc = gih[(b * 50 + t) * 512 + tid];
        const float4* h4 = (const float4*)h;
#pragma unroll 8
        for (int k4 = 0; k4 < 32; ++k4) acc += dot4(wr[k4], h4[k4]);
        gates[tid] = acc;
        __syncthreads();
        if (tid < 128) {
            float gi = gates[tid], gf = gates[128 + tid], gg = gates[256 + tid], go = gates[384 + tid];
            c = sigf(gf) * c + sigf(gi) * tanhf_fast(gg);
            float hn = sigf(go) * tanhf_fast(c);
            h[tid] = hn;
            enc_out[(b * 50 + t) * 128 + tid] = hn;
        }
    }
}

// ---------------------------------------------------------------------------
// K4: decoder LSTM + attention + output projection. One block per batch, 512 thr.
// att_src[b] and enc_out[b] staged in LDS (2 x 25.6 KB).
// ---------------------------------------------------------------------------
__global__ void __launch_bounds__(512) dec_rnn_kernel(const float* __restrict__ gih,
                                                      const float* __restrict__ Whh,
                                                      const float* __restrict__ enc_out,
                                                      const float* __restrict__ att_src,
                                                      const float* __restrict__ w1t,
                                                      const float* __restrict__ b1t,
                                                      const float* __restrict__ w2,
                                                      const float* __restrict__ b2,
                                                      const float* __restrict__ out_w,
                                                      const float* __restrict__ out_b,
                                                      ushort_t* __restrict__ final_bf)
{
    int b = blockIdx.x, tid = threadIdx.x;
    __shared__ __align__(16) float as_[50 * 128];
    __shared__ __align__(16) float eo[50 * 128];
    __shared__ __align__(16) float h[128];
    __shared__ __align__(16) float attv[128];
    __shared__ float gates[512];
    __shared__ float attt[128];
    __shared__ float sc[64];
    for (int i = tid; i < 50 * 128; i += 512) {
        as_[i] = att_src[b * 6400 + i];
        eo[i] = enc_out[b * 6400 + i];
    }
    float c = 0.f;
    if (tid < 128) h[tid] = 0.f;
    int lane = tid & 63, wv = tid >> 6;
    float w2a = w2[lane], w2b = w2[lane + 64];
    float b2s = b2[0];
    const float4* whr = (const float4*)(Whh + tid * 128);
    const float4* h4 = (const float4*)h;
    for (int t = 0; t < 49; ++t) {
        __syncthreads();
        // gates
        float acc = gih[(b * 49 + t) * 512 + tid];
#pragma unroll 8
        for (int k4 = 0; k4 < 32; ++k4) acc += dot4(whr[k4], h4[k4]);
        gates[tid] = acc;
        __syncthreads();
        // LSTM pointwise
        if (tid < 128) {
            float gi = gates[tid], gf = gates[128 + tid], gg = gates[256 + tid], go = gates[384 + tid];
            c = sigf(gf) * c + sigf(gi) * tanhf_fast(gg);
            h[tid] = sigf(go) * tanhf_fast(c);
        }
        __syncthreads();
        // att_tgt = h @ w1t^T + b1t
        if (tid < 128) {
            const float4* wt = (const float4*)(w1t + tid * 128);
            float a2 = b1t[tid];
#pragma unroll 8
            for (int k4 = 0; k4 < 32; ++k4) a2 += dot4(wt[k4], h4[k4]);
            attt[tid] = a2;
        }
        __syncthreads();
        // scores[s] = b2 + sum_a w2[a] * tanh(att_src[s,a] + att_tgt[a])
        {
            float ta = attt[lane], tb = attt[lane + 64];
            for (int s = wv; s < 50; s += 8) {
                float v = w2a * tanhf_fast(as_[s * 128 + lane] + ta)
                        + w2b * tanhf_fast(as_[s * 128 + 64 + lane] + tb);
#pragma unroll
                for (int off = 32; off; off >>= 1) v += __shfl_down(v, off);
                if (lane == 0) sc[s] = v + b2s;
            }
        }
        __syncthreads();
        // softmax over 50 (wave 0)
        if (tid < 64) {
            float x = (tid < 50) ? sc[tid] : -1e30f;
            float m = x;
#pragma unroll
            for (int off = 32; off; off >>= 1) m = fmaxf(m, __shfl_xor(m, off));
            float e = (tid < 50) ? __expf(x - m) : 0.f;
            float ssum = e;
#pragma unroll
            for (int off = 32; off; off >>= 1) ssum += __shfl_xor(ssum, off);
            if (tid < 50) sc[tid] = e / ssum;
        }
        __syncthreads();
        // att_vec
        if (tid < 128) {
            float av = 0.f;
            for (int s = 0; s < 50; ++s) av += sc[s] * eo[s * 128 + tid];
            attv[tid] = av;
        }
        __syncthreads();
        // final = tanh([h, att_vec] @ out_w^T + out_b)  -> bf16
        if (tid < 128) {
            const float4* wo = (const float4*)(out_w + tid * 256);
            const float4* av4 = (const float4*)attv;
            float a3 = out_b[tid];
#pragma unroll 8
            for (int k4 = 0; k4 < 32; ++k4) a3 += dot4(wo[k4], h4[k4]);
#pragma unroll 8
            for (int k4 = 0; k4 < 32; ++k4) a3 += dot4(wo[32 + k4], av4[k4]);
            final_bf[(b * 49 + t) * 128 + tid] = f2bf(tanhf_fast(a3));
        }
    }
}

// ---------------------------------------------------------------------------
// K5: fp32 -> bf16 cast (sm_w), 4 elems/thread
// ---------------------------------------------------------------------------
__global__ void cast_bf16_kernel(const float* __restrict__ x, ushort_t* __restrict__ y, int n)
{
    int i = (blockIdx.x * blockDim.x + threadIdx.x) * 4;
    if (i + 3 < n) {
        float4 v = *(const float4*)(x + i);
        y[i + 0] = f2bf(v.x);
        y[i + 1] = f2bf(v.y);
        y[i + 2] = f2bf(v.z);
        y[i + 3] = f2bf(v.w);
    }
}

// ---------------------------------------------------------------------------
// K6: logits = final(1568x128) @ sm_w^T(128x32000) + sm_b, bf16 MFMA.
// Block = 4 waves. Wave w: rows [mt*16, mt*16+16), mt = blockIdx.y*4+w;
// cols [blockIdx.x*128, +128) shared across waves (B frags L1-resident).
// v_mfma_f32_16x16x32_bf16: A[m=lane&15][k=quad*8+j]; B symmetric (N x K rows);
// C: row=quad*4+reg, col=lane&15.
// ---------------------------------------------------------------------------
typedef __attribute__((ext_vector_type(8))) short bfrag;
typedef __attribute__((ext_vector_type(4))) float f32x4;

__global__ void __launch_bounds__(256) logits_gemm_kernel(const ushort_t* __restrict__ A,
                                                          const ushort_t* __restrict__ Bw,
                                                          const float* __restrict__ bias,
                                                          float* __restrict__ out)
{
    int wv = threadIdx.x >> 6, lane = threadIdx.x & 63;
    int mt = blockIdx.y * 4 + wv;
    if (mt >= 98) return;  // M = 1568 = 98 * 16; wave-uniform exit, no syncthreads in kernel
    int nbase = blockIdx.x * 128;
    int r = lane & 15;
    int kq = (lane >> 4) * 8;

    const ushort_t* ap = A + (mt * 16 + r) * 128 + kq;
    bfrag a0 = *(const bfrag*)(ap);
    bfrag a1 = *(const bfrag*)(ap + 32);
    bfrag a2 = *(const bfrag*)(ap + 64);
    bfrag a3 = *(const bfrag*)(ap + 96);

#pragma unroll
    for (int vt = 0; vt < 8; ++vt) {
        const ushort_t* bp = Bw + (nbase + vt * 16 + r) * 128 + kq;
        bfrag b0 = *(const bfrag*)(bp);
        bfrag b1 = *(const bfrag*)(bp + 32);
        bfrag b2 = *(const bfrag*)(bp + 64);
        bfrag b3 = *(const bfrag*)(bp + 96);
        f32x4 acc = {0.f, 0.f, 0.f, 0.f};
        acc = __builtin_amdgcn_mfma_f32_16x16x32_bf16(a0, b0, acc, 0, 0, 0);
        acc = __builtin_amdgcn_mfma_f32_16x16x32_bf16(a1, b1, acc, 0, 0, 0);
        acc = __builtin_amdgcn_mfma_f32_16x16x32_bf16(a2, b2, acc, 0, 0, 0);
        acc = __builtin_amdgcn_mfma_f32_16x16x32_bf16(a3, b3, acc, 0, 0, 0);
        int col = nbase + vt * 16 + r;
        float bs = bias[col];
        int mrow0 = mt * 16 + (lane >> 4) * 4;
#pragma unroll
        for (int i = 0; i < 4; ++i) out[(mrow0 + i) * 32000 + col] = acc[i] + bs;
    }
}

extern "C" void kernel_launch(void* const* d_in, const int* in_sizes, int n_in,
                              void* d_out, int out_size, void* d_ws, size_t ws_size,
                              hipStream_t stream)
{
    const int* src      = (const int*)d_in[0];
    const int* trg      = (const int*)d_in[1];
    const float* emb_src = (const float*)d_in[2];
    const float* emb_trg = (const float*)d_in[3];
    const float* enc_Wih = (const float*)d_in[4];
    const float* enc_Whh = (const float*)d_in[5];
    const float* enc_bih = (const float*)d_in[6];
    const float* enc_bhh = (const float*)d_in[7];
    const float* dec_Wih = (const float*)d_in[8];
    const float* dec_Whh = (const float*)d_in[9];
    const float* dec_bih = (const float*)d_in[10];
    const float* dec_bhh = (const float*)d_in[11];
    const float* att_w1s = (const float*)d_in[12];
    const float* att_b1s = (const float*)d_in[13];
    const float* att_w1t = (const float*)d_in[14];
    const float* att_b1t = (const float*)d_in[15];
    const float* att_w2  = (const float*)d_in[16];
    const float* att_b2  = (const float*)d_in[17];
    const float* out_w   = (const float*)d_in[18];
    const float* out_b   = (const float*)d_in[19];
    const float* sm_w    = (const float*)d_in[20];
    const float* sm_b    = (const float*)d_in[21];
    float* out = (float*)d_out;

    char* ws = (char*)d_ws;
    float*    gih_enc = (float*)(ws);                      // 1600*512*4 = 3,276,800
    float*    gih_dec = (float*)(ws + 3276800);            // 1568*512*4 = 3,211,264
    float*    enc_out = (float*)(ws + 6488064);            // 1600*128*4 =   819,200
    float*    att_src = (float*)(ws + 7307264);            // 1600*128*4 =   819,200
    ushort_t* fin_bf  = (ushort_t*)(ws + 8126464);         // 1568*128*2 =   401,408
    ushort_t* smw_bf  = (ushort_t*)(ws + 8527872);         // 32000*128*2 = 8,192,000
                                                           // total ~16.7 MB

    // parallel pre-work (no recurrence deps)
    tok_gemv_kernel<<<400, 512, 0, stream>>>(emb_src, src, 0, enc_Wih, enc_bih, enc_bhh, gih_enc, 1600);
    tok_gemv_kernel<<<392, 512, 0, stream>>>(emb_trg, trg, 49, dec_Wih, dec_bih, dec_bhh, gih_dec, 1568);
    cast_bf16_kernel<<<4000, 256, 0, stream>>>(sm_w, smw_bf, 32000 * 128);

    // recurrent chain
    enc_rnn_kernel<<<32, 512, 0, stream>>>(gih_enc, enc_Whh, enc_out);
    tok_gemv_kernel<<<400, 128, 0, stream>>>(enc_out, nullptr, 0, att_w1s, att_b1s, nullptr, att_src, 1600);
    dec_rnn_kernel<<<32, 512, 0, stream>>>(gih_dec, dec_Whh, enc_out, att_src,
                                           att_w1t, att_b1t, att_w2, att_b2, out_w, out_b, fin_bf);

    // big output GEMM (bf16 MFMA, fp32 accumulate)
    logits_gemm_kernel<<<dim3(250, 25), 256, 0, stream>>>(fin_bf, smw_bf, sm_b, out);
}

// Round 2
// 1204.351 us; speedup vs baseline: 1.3040x; 1.3040x over previous
//
#include <hip/hip_runtime.h>

typedef unsigned short ushort_t;

__device__ __forceinline__ float sigf(float x) { return 1.0f / (1.0f + __expf(-x)); }
__device__ __forceinline__ float tanhf_fast(float x) { return 1.0f - 2.0f / (__expf(2.0f * x) + 1.0f); }
__device__ __forceinline__ ushort_t f2bf(float f) {
    unsigned u = __float_as_uint(f);
    unsigned r = (u + 0x7fffu + ((u >> 16) & 1u)) >> 16;
    return (ushort_t)r;
}

// ---------------------------------------------------------------------------
// K0: fp32 transpose (R x C) -> (C x R), tiled 32x32 via LDS.
// ---------------------------------------------------------------------------
__global__ void transpose_kernel(const float* __restrict__ in, float* __restrict__ out,
                                 int R, int C)
{
    __shared__ float tile[32][33];
    int c0 = blockIdx.x * 32, r0 = blockIdx.y * 32;
    int x = threadIdx.x, y = threadIdx.y;  // block (32, 8)
#pragma unroll
    for (int i = 0; i < 32; i += 8) {
        int r = r0 + y + i, c = c0 + x;
        if (r < R && c < C) tile[y + i][x] = in[r * C + c];
    }
    __syncthreads();
#pragma unroll
    for (int i = 0; i < 32; i += 8) {
        int r = r0 + x, c = c0 + y + i;
        if (r < R && c < C) out[c * R + r] = tile[x][y + i];
    }
}

// ---------------------------------------------------------------------------
// K1/K3: out[n][j] = b1[j] (+ b2[j]) + sum_k X[row(n)][k] * WT[k*J + j]
// WT is the TRANSPOSED weight (K=128 rows, J cols) -> coalesced in j.
// 4 tokens per block, blockDim = J.
// ---------------------------------------------------------------------------
__global__ void tok_gemv_kernel(const float* __restrict__ X,
                                const int* __restrict__ toks,
                                int divv,
                                const float* __restrict__ WT,
                                const float* __restrict__ b1,
                                const float* __restrict__ b2,
                                float* __restrict__ out,
                                int ntok)
{
    __shared__ __align__(16) float xs[4 * 128];
    int J = blockDim.x;
    int n0 = blockIdx.x * 4;
    for (int i = threadIdx.x; i < 4 * 128; i += J) {
        int tt = i >> 7, k = i & 127;
        int n = n0 + tt;
        if (n >= ntok) n = ntok - 1;
        int row;
        if (!toks) row = n;
        else if (divv == 0) row = toks[n];
        else { int bb = n / divv; int t = n - bb * divv; row = toks[bb * (divv + 1) + t]; }
        xs[i] = X[row * 128 + k];
    }
    __syncthreads();
    int j = threadIdx.x;
    float bias = b1[j] + (b2 ? b2[j] : 0.0f);
    const float4* x0 = (const float4*)(xs);
    const float4* x1 = (const float4*)(xs + 128);
    const float4* x2 = (const float4*)(xs + 256);
    const float4* x3 = (const float4*)(xs + 384);
    float a0 = 0.f, a1 = 0.f, a2 = 0.f, a3 = 0.f;
#pragma unroll 8
    for (int k4 = 0; k4 < 32; ++k4) {
        float4 v0 = x0[k4], v1 = x1[k4], v2 = x2[k4], v3 = x3[k4];
        float w0 = WT[(k4 * 4 + 0) * J + j];
        float w1 = WT[(k4 * 4 + 1) * J + j];
        float w2_ = WT[(k4 * 4 + 2) * J + j];
        float w3 = WT[(k4 * 4 + 3) * J + j];
        a0 += v0.x * w0 + v0.y * w1 + v0.z * w2_ + v0.w * w3;
        a1 += v1.x * w0 + v1.y * w1 + v1.z * w2_ + v1.w * w3;
        a2 += v2.x * w0 + v2.y * w1 + v2.z * w2_ + v2.w * w3;
        a3 += v3.x * w0 + v3.y * w1 + v3.z * w2_ + v3.w * w3;
    }
    float accs[4] = {a0, a1, a2, a3};
#pragma unroll
    for (int tt = 0; tt < 4; ++tt) {
        int n = n0 + tt;
        if (n < ntok) out[n * J + j] = bias + accs[tt];
    }
}

// ---------------------------------------------------------------------------
// K2: encoder LSTM recurrence. One block per batch element, 512 threads.
// WhhT is transposed (128 x 512): gates[j] = gih + sum_k h[k]*WhhT[k*512+j]
// ---------------------------------------------------------------------------
__global__ void __launch_bounds__(512) enc_rnn_kernel(const float* __restrict__ gih,
                                                      const float* __restrict__ WhhT,
                                                      float* __restrict__ enc_out)
{
    int b = blockIdx.x, tid = threadIdx.x;
    __shared__ __align__(16) float h[128];
    __shared__ float gates[512];
    float c = 0.f;
    if (tid < 128) h[tid] = 0.f;
    const float4* h4 = (const float4*)h;
    const float* gbase = gih + b * 50 * 512 + tid;
    for (int t = 0; t < 50; ++t) {
        __syncthreads();
        float acc = gbase[t * 512];
#pragma unroll 8
        for (int k4 = 0; k4 < 32; ++k4) {
            float4 hv = h4[k4];
            acc += hv.x * WhhT[(k4 * 4 + 0) * 512 + tid];
            acc += hv.y * WhhT[(k4 * 4 + 1) * 512 + tid];
            acc += hv.z * WhhT[(k4 * 4 + 2) * 512 + tid];
            acc += hv.w * WhhT[(k4 * 4 + 3) * 512 + tid];
        }
        gates[tid] = acc;
        __syncthreads();
        if (tid < 128) {
            float gi = gates[tid], gf = gates[128 + tid], gg = gates[256 + tid], go = gates[384 + tid];
            c = sigf(gf) * c + sigf(gi) * tanhf_fast(gg);
            float hn = sigf(go) * tanhf_fast(c);
            h[tid] = hn;
            enc_out[(b * 50 + t) * 128 + tid] = hn;
        }
    }
}

// ---------------------------------------------------------------------------
// K4: decoder LSTM + attention + output projection. One block per batch, 512 thr.
// All weight mats transposed -> coalesced. k-split partials for att_tgt/final.
// ---------------------------------------------------------------------------
__global__ void __launch_bounds__(512) dec_rnn_kernel(const float* __restrict__ gih,
                                                      const float* __restrict__ WhhT,   // 128x512
                                                      const float* __restrict__ enc_out,
                                                      const float* __restrict__ att_src,
                                                      const float* __restrict__ w1tT,   // 128x128
                                                      const float* __restrict__ b1t,
                                                      const float* __restrict__ w2,
                                                      const float* __restrict__ b2,
                                                      const float* __restrict__ out_wT, // 256x128
                                                      const float* __restrict__ out_b,
                                                      ushort_t* __restrict__ final_bf)
{
    int b = blockIdx.x, tid = threadIdx.x;
    __shared__ __align__(16) float as_[50 * 128];
    __shared__ __align__(16) float eo[50 * 128];
    __shared__ __align__(16) float h[128];
    __shared__ __align__(16) float attv[128];
    __shared__ float gates[512];
    __shared__ float part[512];
    __shared__ float sc[64];

    {
        const float4* asg = (const float4*)(att_src + b * 6400);
        const float4* eog = (const float4*)(enc_out + b * 6400);
        float4* as4 = (float4*)as_;
        float4* eo4 = (float4*)eo;
        for (int i = tid; i < 1600; i += 512) { as4[i] = asg[i]; eo4[i] = eog[i]; }
    }
    float c = 0.f;
    if (tid < 128) h[tid] = 0.f;
    int lane = tid & 63, wv = tid >> 6;
    int jj = tid & 127, g = tid >> 7;
    float w2a = w2[lane], w2b = w2[lane + 64];
    float b2s = b2[0];
    float b1ta = b1t[lane], b1tb = b1t[lane + 64];
    float outb = (tid < 128) ? out_b[tid] : 0.f;
    const float4* h4 = (const float4*)h;
    const float* gbase = gih + b * 49 * 512 + tid;

    for (int t = 0; t < 49; ++t) {
        __syncthreads();
        // A: gates (all 512 threads, coalesced WhhT)
        float acc = gbase[t * 512];
#pragma unroll 8
        for (int k4 = 0; k4 < 32; ++k4) {
            float4 hv = h4[k4];
            acc += hv.x * WhhT[(k4 * 4 + 0) * 512 + tid];
            acc += hv.y * WhhT[(k4 * 4 + 1) * 512 + tid];
            acc += hv.z * WhhT[(k4 * 4 + 2) * 512 + tid];
            acc += hv.w * WhhT[(k4 * 4 + 3) * 512 + tid];
        }
        gates[tid] = acc;
        __syncthreads();
        // B: LSTM pointwise
        if (tid < 128) {
            float gi = gates[tid], gf = gates[128 + tid], gg = gates[256 + tid], go = gates[384 + tid];
            c = sigf(gf) * c + sigf(gi) * tanhf_fast(gg);
            h[tid] = sigf(go) * tanhf_fast(c);
        }
        __syncthreads();
        // C: att_tgt partials: group g covers k in [g*32, g*32+32)
        {
            float p = 0.f;
            const float4* hb = (const float4*)(h + g * 32);
#pragma unroll
            for (int k4 = 0; k4 < 8; ++k4) {
                float4 hv = hb[k4];
                int k = g * 32 + k4 * 4;
                p += hv.x * w1tT[(k + 0) * 128 + jj];
                p += hv.y * w1tT[(k + 1) * 128 + jj];
                p += hv.z * w1tT[(k + 2) * 128 + jj];
                p += hv.w * w1tT[(k + 3) * 128 + jj];
            }
            part[g * 128 + jj] = p;
        }
        __syncthreads();
        // D: scores (attt reduction folded in, redundant per wave)
        {
            float ta = b1ta + part[lane]      + part[128 + lane] + part[256 + lane] + part[384 + lane];
            float tb = b1tb + part[64 + lane] + part[192 + lane] + part[320 + lane] + part[448 + lane];
            for (int s = wv; s < 50; s += 8) {
                float v = w2a * tanhf_fast(as_[s * 128 + lane] + ta)
                        + w2b * tanhf_fast(as_[s * 128 + 64 + lane] + tb);
#pragma unroll
                for (int off = 32; off; off >>= 1) v += __shfl_down(v, off);
                if (lane == 0) sc[s] = v + b2s;
            }
        }
        __syncthreads();
        // E: softmax over 50 (wave 0)
        if (tid < 64) {
            float x = (tid < 50) ? sc[tid] : -1e30f;
            float m = x;
#pragma unroll
            for (int off = 32; off; off >>= 1) m = fmaxf(m, __shfl_xor(m, off));
            float e = (tid < 50) ? __expf(x - m) : 0.f;
            float ssum = e;
#pragma unroll
            for (int off = 32; off; off >>= 1) ssum += __shfl_xor(ssum, off);
            if (tid < 50) sc[tid] = e / ssum;
        }
        __syncthreads();
        // F: att_vec
        if (tid < 128) {
            float av = 0.f;
            for (int s = 0; s < 50; ++s) av += sc[s] * eo[s * 128 + tid];
            attv[tid] = av;
        }
        __syncthreads();
        // G1: final partials: group g covers k in [g*64, g*64+64) of cat=[h|attv]
        {
            const float4* cb = (g < 2) ? (const float4*)(h + g * 64)
                                       : (const float4*)(attv + (g - 2) * 64);
            float p = 0.f;
#pragma unroll
            for (int k4 = 0; k4 < 16; ++k4) {
                float4 cv = cb[k4];
                int k = g * 64 + k4 * 4;
                p += cv.x * out_wT[(k + 0) * 128 + jj];
                p += cv.y * out_wT[(k + 1) * 128 + jj];
                p += cv.z * out_wT[(k + 2) * 128 + jj];
                p += cv.w * out_wT[(k + 3) * 128 + jj];
            }
            part[g * 128 + jj] = p;
        }
        __syncthreads();
        // G2: reduce + tanh + bf16 store
        if (tid < 128) {
            float a3 = outb + part[tid] + part[128 + tid] + part[256 + tid] + part[384 + tid];
            final_bf[(b * 49 + t) * 128 + tid] = f2bf(tanhf_fast(a3));
        }
    }
}

// ---------------------------------------------------------------------------
// K5: fp32 -> bf16 cast (sm_w), 4 elems/thread
// ---------------------------------------------------------------------------
__global__ void cast_bf16_kernel(const float* __restrict__ x, ushort_t* __restrict__ y, int n)
{
    int i = (blockIdx.x * blockDim.x + threadIdx.x) * 4;
    if (i + 3 < n) {
        float4 v = *(const float4*)(x + i);
        y[i + 0] = f2bf(v.x);
        y[i + 1] = f2bf(v.y);
        y[i + 2] = f2bf(v.z);
        y[i + 3] = f2bf(v.w);
    }
}

// ---------------------------------------------------------------------------
// K6: logits = final(1568x128) @ sm_w^T(128x32000) + sm_b, bf16 MFMA.
// ---------------------------------------------------------------------------
typedef __attribute__((ext_vector_type(8))) short bfrag;
typedef __attribute__((ext_vector_type(4))) float f32x4;

__global__ void __launch_bounds__(256) logits_gemm_kernel(const ushort_t* __restrict__ A,
                                                          const ushort_t* __restrict__ Bw,
                                                          const float* __restrict__ bias,
                                                          float* __restrict__ out)
{
    int wv = threadIdx.x >> 6, lane = threadIdx.x & 63;
    int mt = blockIdx.y * 4 + wv;
    if (mt >= 98) return;  // M = 1568 = 98*16; wave-uniform exit
    int nbase = blockIdx.x * 128;
    int r = lane & 15;
    int kq = (lane >> 4) * 8;

    const ushort_t* ap = A + (mt * 16 + r) * 128 + kq;
    bfrag a0 = *(const bfrag*)(ap);
    bfrag a1 = *(const bfrag*)(ap + 32);
    bfrag a2 = *(const bfrag*)(ap + 64);
    bfrag a3 = *(const bfrag*)(ap + 96);

#pragma unroll
    for (int vt = 0; vt < 8; ++vt) {
        const ushort_t* bp = Bw + (nbase + vt * 16 + r) * 128 + kq;
        bfrag b0 = *(const bfrag*)(bp);
        bfrag b1 = *(const bfrag*)(bp + 32);
        bfrag b2 = *(const bfrag*)(bp + 64);
        bfrag b3 = *(const bfrag*)(bp + 96);
        f32x4 acc = {0.f, 0.f, 0.f, 0.f};
        acc = __builtin_amdgcn_mfma_f32_16x16x32_bf16(a0, b0, acc, 0, 0, 0);
        acc = __builtin_amdgcn_mfma_f32_16x16x32_bf16(a1, b1, acc, 0, 0, 0);
        acc = __builtin_amdgcn_mfma_f32_16x16x32_bf16(a2, b2, acc, 0, 0, 0);
        acc = __builtin_amdgcn_mfma_f32_16x16x32_bf16(a3, b3, acc, 0, 0, 0);
        int col = nbase + vt * 16 + r;
        float bs = bias[col];
        int mrow0 = mt * 16 + (lane >> 4) * 4;
#pragma unroll
        for (int i = 0; i < 4; ++i) out[(mrow0 + i) * 32000 + col] = acc[i] + bs;
    }
}

extern "C" void kernel_launch(void* const* d_in, const int* in_sizes, int n_in,
                              void* d_out, int out_size, void* d_ws, size_t ws_size,
                              hipStream_t stream)
{
    const int* src      = (const int*)d_in[0];
    const int* trg      = (const int*)d_in[1];
    const float* emb_src = (const float*)d_in[2];
    const float* emb_trg = (const float*)d_in[3];
    const float* enc_Wih = (const float*)d_in[4];
    const float* enc_Whh = (const float*)d_in[5];
    const float* enc_bih = (const float*)d_in[6];
    const float* enc_bhh = (const float*)d_in[7];
    const float* dec_Wih = (const float*)d_in[8];
    const float* dec_Whh = (const float*)d_in[9];
    const float* dec_bih = (const float*)d_in[10];
    const float* dec_bhh = (const float*)d_in[11];
    const float* att_w1s = (const float*)d_in[12];
    const float* att_b1s = (const float*)d_in[13];
    const float* att_w1t = (const float*)d_in[14];
    const float* att_b1t = (const float*)d_in[15];
    const float* att_w2  = (const float*)d_in[16];
    const float* att_b2  = (const float*)d_in[17];
    const float* out_w   = (const float*)d_in[18];
    const float* out_b   = (const float*)d_in[19];
    const float* sm_w    = (const float*)d_in[20];
    const float* sm_b    = (const float*)d_in[21];
    float* out = (float*)d_out;

    char* ws = (char*)d_ws;
    float*    gih_enc = (float*)(ws);                      // 3,276,800
    float*    gih_dec = (float*)(ws + 3276800);            // 3,211,264
    float*    enc_out = (float*)(ws + 6488064);            //   819,200
    float*    att_src = (float*)(ws + 7307264);            //   819,200
    ushort_t* fin_bf  = (ushort_t*)(ws + 8126464);         //   401,408
    ushort_t* smw_bf  = (ushort_t*)(ws + 8527872);         // 8,192,000
    float*    WihT_e  = (float*)(ws + 16719872);           //   262,144
    float*    WihT_d  = (float*)(ws + 16982016);           //   262,144
    float*    WhhT_e  = (float*)(ws + 17244160);           //   262,144
    float*    WhhT_d  = (float*)(ws + 17506304);           //   262,144
    float*    w1sT    = (float*)(ws + 17768448);           //    65,536
    float*    w1tT    = (float*)(ws + 17833984);           //    65,536
    float*    outwT   = (float*)(ws + 17899520);           //   131,072
                                                           // total ~18.0 MB

    // one-shot weight transposes (cheap)
    dim3 tb(32, 8);
    transpose_kernel<<<dim3(4, 16), tb, 0, stream>>>(enc_Wih, WihT_e, 512, 128);
    transpose_kernel<<<dim3(4, 16), tb, 0, stream>>>(dec_Wih, WihT_d, 512, 128);
    transpose_kernel<<<dim3(4, 16), tb, 0, stream>>>(enc_Whh, WhhT_e, 512, 128);
    transpose_kernel<<<dim3(4, 16), tb, 0, stream>>>(dec_Whh, WhhT_d, 512, 128);
    transpose_kernel<<<dim3(4, 4),  tb, 0, stream>>>(att_w1s, w1sT, 128, 128);
    transpose_kernel<<<dim3(4, 4),  tb, 0, stream>>>(att_w1t, w1tT, 128, 128);
    transpose_kernel<<<dim3(8, 4),  tb, 0, stream>>>(out_w, outwT, 128, 256);

    // parallel pre-work
    tok_gemv_kernel<<<400, 512, 0, stream>>>(emb_src, src, 0, WihT_e, enc_bih, enc_bhh, gih_enc, 1600);
    tok_gemv_kernel<<<392, 512, 0, stream>>>(emb_trg, trg, 49, WihT_d, dec_bih, dec_bhh, gih_dec, 1568);
    cast_bf16_kernel<<<4000, 256, 0, stream>>>(sm_w, smw_bf, 32000 * 128);

    // recurrent chain
    enc_rnn_kernel<<<32, 512, 0, stream>>>(gih_enc, WhhT_e, enc_out);
    tok_gemv_kernel<<<400, 128, 0, stream>>>(enc_out, nullptr, 0, w1sT, att_b1s, nullptr, att_src, 1600);
    dec_rnn_kernel<<<32, 512, 0, stream>>>(gih_dec, WhhT_d, enc_out, att_src,
                                           w1tT, att_b1t, att_w2, att_b2, outwT, out_b, fin_bf);

    // big output GEMM (bf16 MFMA, fp32 accumulate)
    logits_gemm_kernel<<<dim3(250, 25), 256, 0, stream>>>(fin_bf, smw_bf, sm_b, out);
}

// Round 3
// 497.488 us; speedup vs baseline: 3.1568x; 2.4209x over previous
//
#include <hip/hip_runtime.h>

typedef unsigned short ushort_t;

__device__ __forceinline__ float sigf(float x) { return 1.0f / (1.0f + __expf(-x)); }
__device__ __forceinline__ float tanhf_fast(float x) { return 1.0f - 2.0f / (__expf(2.0f * x) + 1.0f); }
__device__ __forceinline__ ushort_t f2bf(float f) {
    unsigned u = __float_as_uint(f);
    unsigned r = (u + 0x7fffu + ((u >> 16) & 1u)) >> 16;
    return (ushort_t)r;
}

// ---------------------------------------------------------------------------
// K0: fp32 transpose (R x C) -> (C x R), tiled 32x32 via LDS.
// ---------------------------------------------------------------------------
__global__ void transpose_kernel(const float* __restrict__ in, float* __restrict__ out,
                                 int R, int C)
{
    __shared__ float tile[32][33];
    int c0 = blockIdx.x * 32, r0 = blockIdx.y * 32;
    int x = threadIdx.x, y = threadIdx.y;  // block (32, 8)
#pragma unroll
    for (int i = 0; i < 32; i += 8) {
        int r = r0 + y + i, c = c0 + x;
        if (r < R && c < C) tile[y + i][x] = in[r * C + c];
    }
    __syncthreads();
#pragma unroll
    for (int i = 0; i < 32; i += 8) {
        int r = r0 + x, c = c0 + y + i;
        if (r < R && c < C) out[c * R + r] = tile[x][y + i];
    }
}

// ---------------------------------------------------------------------------
// K1: out[n][j] = b1[j] (+ b2[j]) + sum_k X[row(n)][k] * WT[k*J + j]
// WT transposed (128 rows, J cols) -> coalesced in j. 4 tokens/block.
// ---------------------------------------------------------------------------
__global__ void tok_gemv_kernel(const float* __restrict__ X,
                                const int* __restrict__ toks,
                                int divv,
                                const float* __restrict__ WT,
                                const float* __restrict__ b1,
                                const float* __restrict__ b2,
                                float* __restrict__ out,
                                int ntok)
{
    __shared__ __align__(16) float xs[4 * 128];
    int J = blockDim.x;
    int n0 = blockIdx.x * 4;
    for (int i = threadIdx.x; i < 4 * 128; i += J) {
        int tt = i >> 7, k = i & 127;
        int n = n0 + tt;
        if (n >= ntok) n = ntok - 1;
        int row;
        if (!toks) row = n;
        else if (divv == 0) row = toks[n];
        else { int bb = n / divv; int t = n - bb * divv; row = toks[bb * (divv + 1) + t]; }
        xs[i] = X[row * 128 + k];
    }
    __syncthreads();
    int j = threadIdx.x;
    float bias = b1[j] + (b2 ? b2[j] : 0.0f);
    const float4* x0 = (const float4*)(xs);
    const float4* x1 = (const float4*)(xs + 128);
    const float4* x2 = (const float4*)(xs + 256);
    const float4* x3 = (const float4*)(xs + 384);
    float a0 = 0.f, a1 = 0.f, a2 = 0.f, a3 = 0.f;
#pragma unroll 8
    for (int k4 = 0; k4 < 32; ++k4) {
        float4 v0 = x0[k4], v1 = x1[k4], v2 = x2[k4], v3 = x3[k4];
        float w0 = WT[(k4 * 4 + 0) * J + j];
        float w1 = WT[(k4 * 4 + 1) * J + j];
        float w2_ = WT[(k4 * 4 + 2) * J + j];
        float w3 = WT[(k4 * 4 + 3) * J + j];
        a0 += v0.x * w0 + v0.y * w1 + v0.z * w2_ + v0.w * w3;
        a1 += v1.x * w0 + v1.y * w1 + v1.z * w2_ + v1.w * w3;
        a2 += v2.x * w0 + v2.y * w1 + v2.z * w2_ + v2.w * w3;
        a3 += v3.x * w0 + v3.y * w1 + v3.z * w2_ + v3.w * w3;
    }
    float accs[4] = {a0, a1, a2, a3};
#pragma unroll
    for (int tt = 0; tt < 4; ++tt) {
        int n = n0 + tt;
        if (n < ntok) out[n * J + j] = bias + accs[tt];
    }
}

// ---------------------------------------------------------------------------
// K2: combined LSTM recurrences. Blocks 0..31: encoder (T=50), 32..63: decoder
// (T=49). Whh row tid cached in 128 VGPRs -> zero global loads in the loop.
// Per step: LDS h read + 128 reg-FMA + 2 barriers + pointwise.
// ---------------------------------------------------------------------------
__global__ void __launch_bounds__(512, 2) rnn_kernel(const float* __restrict__ gih_enc,
                                                     const float* __restrict__ enc_Whh,
                                                     const float* __restrict__ gih_dec,
                                                     const float* __restrict__ dec_Whh,
                                                     float* __restrict__ enc_out,
                                                     float* __restrict__ hdec)
{
    bool is_enc = blockIdx.x < 32;
    int b = is_enc ? blockIdx.x : blockIdx.x - 32;
    int T = is_enc ? 50 : 49;
    const float* gih = is_enc ? gih_enc : gih_dec;
    const float* Whh = is_enc ? enc_Whh : dec_Whh;
    float* hout = is_enc ? enc_out : hdec;

    int tid = threadIdx.x;
    __shared__ __align__(16) float h[128];
    __shared__ float gates[512];

    // cache Whh row `tid` (contiguous in original layout) in registers
    float4 w[32];
    const float4* wr = (const float4*)(Whh + tid * 128);
#pragma unroll
    for (int k = 0; k < 32; ++k) w[k] = wr[k];

    float c = 0.f;
    if (tid < 128) h[tid] = 0.f;
    const float* gb = gih + b * T * 512 + tid;
    float gnext = gb[0];
    const float4* h4 = (const float4*)h;

    for (int t = 0; t < T; ++t) {
        __syncthreads();
        float acc = gnext;
        if (t + 1 < T) gnext = gb[(t + 1) * 512];  // prefetch (independent of h)
#pragma unroll
        for (int k = 0; k < 32; ++k) {
            float4 hv = h4[k];
            acc += hv.x * w[k].x + hv.y * w[k].y + hv.z * w[k].z + hv.w * w[k].w;
        }
        gates[tid] = acc;
        __syncthreads();
        if (tid < 128) {
            float gi = gates[tid], gf = gates[128 + tid], gg = gates[256 + tid], go = gates[384 + tid];
            c = sigf(gf) * c + sigf(gi) * tanhf_fast(gg);
            float hn = sigf(go) * tanhf_fast(c);
            h[tid] = hn;
            hout[(b * T + t) * 128 + tid] = hn;
        }
    }
}

// ---------------------------------------------------------------------------
// K4: fully parallel attention + output projection. One block per (b,t),
// grid (49, 32), 128 threads. All weight reads coalesced & L2-hot.
// ---------------------------------------------------------------------------
__global__ void __launch_bounds__(128) att_par_kernel(const float* __restrict__ hdec,
                                                      const float* __restrict__ att_src,
                                                      const float* __restrict__ enc_out,
                                                      const float* __restrict__ w1tT,   // 128x128
                                                      const float* __restrict__ b1t,
                                                      const float* __restrict__ w2,
                                                      const float* __restrict__ b2,
                                                      const float* __restrict__ out_wT, // 256x128
                                                      const float* __restrict__ out_b,
                                                      ushort_t* __restrict__ fin_bf)
{
    int t = blockIdx.x, b = blockIdx.y;
    int tid = threadIdx.x, lane = tid & 63, wv = tid >> 6;
    __shared__ __align__(16) float h[128];
    __shared__ __align__(16) float attv[128];
    __shared__ float attt[128];
    __shared__ float sc[64];

    h[tid] = hdec[(b * 49 + t) * 128 + tid];
    __syncthreads();
    const float4* h4 = (const float4*)h;

    // att_tgt = h @ w1t^T + b1t
    {
        float acc = b1t[tid];
#pragma unroll
        for (int k4 = 0; k4 < 32; ++k4) {
            float4 hv = h4[k4];
            int k = k4 * 4;
            acc += hv.x * w1tT[(k + 0) * 128 + tid] + hv.y * w1tT[(k + 1) * 128 + tid]
                 + hv.z * w1tT[(k + 2) * 128 + tid] + hv.w * w1tT[(k + 3) * 128 + tid];
        }
        attt[tid] = acc;
    }
    __syncthreads();
    // scores
    {
        float w2a = w2[lane], w2b = w2[lane + 64], b2s = b2[0];
        float ta = attt[lane], tb = attt[lane + 64];
        const float* asb = att_src + b * 6400;
        for (int s = wv; s < 50; s += 2) {
            float v = w2a * tanhf_fast(asb[s * 128 + lane] + ta)
                    + w2b * tanhf_fast(asb[s * 128 + 64 + lane] + tb);
#pragma unroll
            for (int off = 32; off; off >>= 1) v += __shfl_down(v, off);
            if (lane == 0) sc[s] = v + b2s;
        }
    }
    __syncthreads();
    // softmax over 50 (wave 0)
    if (tid < 64) {
        float x = (tid < 50) ? sc[tid] : -1e30f;
        float m = x;
#pragma unroll
        for (int off = 32; off; off >>= 1) m = fmaxf(m, __shfl_xor(m, off));
        float e = (tid < 50) ? __expf(x - m) : 0.f;
        float ssum = e;
#pragma unroll
        for (int off = 32; off; off >>= 1) ssum += __shfl_xor(ssum, off);
        if (tid < 50) sc[tid] = e / ssum;
    }
    __syncthreads();
    // att_vec
    {
        const float* eob = enc_out + b * 6400;
        float av = 0.f;
        for (int s = 0; s < 50; ++s) av += sc[s] * eob[s * 128 + tid];
        attv[tid] = av;
    }
    __syncthreads();
    // final = tanh([h | attv] @ out_w^T + out_b) -> bf16
    {
        const float4* av4 = (const float4*)attv;
        float a3 = out_b[tid];
#pragma unroll
        for (int k4 = 0; k4 < 32; ++k4) {
            float4 hv = h4[k4];
            int k = k4 * 4;
            a3 += hv.x * out_wT[(k + 0) * 128 + tid] + hv.y * out_wT[(k + 1) * 128 + tid]
                + hv.z * out_wT[(k + 2) * 128 + tid] + hv.w * out_wT[(k + 3) * 128 + tid];
        }
#pragma unroll
        for (int k4 = 0; k4 < 32; ++k4) {
            float4 vv = av4[k4];
            int k = 128 + k4 * 4;
            a3 += vv.x * out_wT[(k + 0) * 128 + tid] + vv.y * out_wT[(k + 1) * 128 + tid]
                + vv.z * out_wT[(k + 2) * 128 + tid] + vv.w * out_wT[(k + 3) * 128 + tid];
        }
        fin_bf[(b * 49 + t) * 128 + tid] = f2bf(tanhf_fast(a3));
    }
}

// ---------------------------------------------------------------------------
// K5: fp32 -> bf16 cast (sm_w), 4 elems/thread
// ---------------------------------------------------------------------------
__global__ void cast_bf16_kernel(const float* __restrict__ x, ushort_t* __restrict__ y, int n)
{
    int i = (blockIdx.x * blockDim.x + threadIdx.x) * 4;
    if (i + 3 < n) {
        float4 v = *(const float4*)(x + i);
        y[i + 0] = f2bf(v.x);
        y[i + 1] = f2bf(v.y);
        y[i + 2] = f2bf(v.z);
        y[i + 3] = f2bf(v.w);
    }
}

// ---------------------------------------------------------------------------
// K6: logits = final(1568x128) @ sm_w^T(128x32000) + sm_b, bf16 MFMA.
// ---------------------------------------------------------------------------
typedef __attribute__((ext_vector_type(8))) short bfrag;
typedef __attribute__((ext_vector_type(4))) float f32x4;

__global__ void __launch_bounds__(256) logits_gemm_kernel(const ushort_t* __restrict__ A,
                                                          const ushort_t* __restrict__ Bw,
                                                          const float* __restrict__ bias,
                                                          float* __restrict__ out)
{
    int wv = threadIdx.x >> 6, lane = threadIdx.x & 63;
    int mt = blockIdx.y * 4 + wv;
    if (mt >= 98) return;  // M = 1568 = 98*16; wave-uniform exit
    int nbase = blockIdx.x * 128;
    int r = lane & 15;
    int kq = (lane >> 4) * 8;

    const ushort_t* ap = A + (mt * 16 + r) * 128 + kq;
    bfrag a0 = *(const bfrag*)(ap);
    bfrag a1 = *(const bfrag*)(ap + 32);
    bfrag a2 = *(const bfrag*)(ap + 64);
    bfrag a3 = *(const bfrag*)(ap + 96);

#pragma unroll
    for (int vt = 0; vt < 8; ++vt) {
        const ushort_t* bp = Bw + (nbase + vt * 16 + r) * 128 + kq;
        bfrag b0 = *(const bfrag*)(bp);
        bfrag b1 = *(const bfrag*)(bp + 32);
        bfrag b2 = *(const bfrag*)(bp + 64);
        bfrag b3 = *(const bfrag*)(bp + 96);
        f32x4 acc = {0.f, 0.f, 0.f, 0.f};
        acc = __builtin_amdgcn_mfma_f32_16x16x32_bf16(a0, b0, acc, 0, 0, 0);
        acc = __builtin_amdgcn_mfma_f32_16x16x32_bf16(a1, b1, acc, 0, 0, 0);
        acc = __builtin_amdgcn_mfma_f32_16x16x32_bf16(a2, b2, acc, 0, 0, 0);
        acc = __builtin_amdgcn_mfma_f32_16x16x32_bf16(a3, b3, acc, 0, 0, 0);
        int col = nbase + vt * 16 + r;
        float bs = bias[col];
        int mrow0 = mt * 16 + (lane >> 4) * 4;
#pragma unroll
        for (int i = 0; i < 4; ++i) out[(mrow0 + i) * 32000 + col] = acc[i] + bs;
    }
}

extern "C" void kernel_launch(void* const* d_in, const int* in_sizes, int n_in,
                              void* d_out, int out_size, void* d_ws, size_t ws_size,
                              hipStream_t stream)
{
    const int* src      = (const int*)d_in[0];
    const int* trg      = (const int*)d_in[1];
    const float* emb_src = (const float*)d_in[2];
    const float* emb_trg = (const float*)d_in[3];
    const float* enc_Wih = (const float*)d_in[4];
    const float* enc_Whh = (const float*)d_in[5];
    const float* enc_bih = (const float*)d_in[6];
    const float* enc_bhh = (const float*)d_in[7];
    const float* dec_Wih = (const float*)d_in[8];
    const float* dec_Whh = (const float*)d_in[9];
    const float* dec_bih = (const float*)d_in[10];
    const float* dec_bhh = (const float*)d_in[11];
    const float* att_w1s = (const float*)d_in[12];
    const float* att_b1s = (const float*)d_in[13];
    const float* att_w1t = (const float*)d_in[14];
    const float* att_b1t = (const float*)d_in[15];
    const float* att_w2  = (const float*)d_in[16];
    const float* att_b2  = (const float*)d_in[17];
    const float* out_w   = (const float*)d_in[18];
    const float* out_b   = (const float*)d_in[19];
    const float* sm_w    = (const float*)d_in[20];
    const float* sm_b    = (const float*)d_in[21];
    float* out = (float*)d_out;

    // Workspace layout (17.1 MB; att_src overlaps dead gih_enc, fin_bf overlaps
    // dead gih_dec — gih_* are only live until rnn_kernel completes).
    char* ws = (char*)d_ws;
    float*    gih_enc = (float*)(ws);                      // 3,276,800 (phase 1-2)
    float*    att_src = (float*)(ws);                      //   819,200 (phase 3+, overlaps)
    float*    gih_dec = (float*)(ws + 3276800);            // 3,211,264 (phase 1-2)
    ushort_t* fin_bf  = (ushort_t*)(ws + 3276800);         //   401,408 (phase 4+, overlaps)
    float*    enc_out = (float*)(ws + 6488064);            //   819,200
    float*    hdec    = (float*)(ws + 7307264);            //   802,816
    ushort_t* smw_bf  = (ushort_t*)(ws + 8110080);         // 8,192,000
    float*    WihT_e  = (float*)(ws + 16302080);           //   262,144
    float*    WihT_d  = (float*)(ws + 16564224);           //   262,144
    float*    w1sT    = (float*)(ws + 16826368);           //    65,536
    float*    w1tT    = (float*)(ws + 16891904);           //    65,536
    float*    outwT   = (float*)(ws + 16957440);           //   131,072 -> 17,088,512 total

    // one-shot weight transposes (Whh no longer needs transposing: rows cached in regs)
    dim3 tb(32, 8);
    transpose_kernel<<<dim3(4, 16), tb, 0, stream>>>(enc_Wih, WihT_e, 512, 128);
    transpose_kernel<<<dim3(4, 16), tb, 0, stream>>>(dec_Wih, WihT_d, 512, 128);
    transpose_kernel<<<dim3(4, 4),  tb, 0, stream>>>(att_w1s, w1sT, 128, 128);
    transpose_kernel<<<dim3(4, 4),  tb, 0, stream>>>(att_w1t, w1tT, 128, 128);
    transpose_kernel<<<dim3(8, 4),  tb, 0, stream>>>(out_w, outwT, 128, 256);

    // parallel pre-work
    tok_gemv_kernel<<<400, 512, 0, stream>>>(emb_src, src, 0, WihT_e, enc_bih, enc_bhh, gih_enc, 1600);
    tok_gemv_kernel<<<392, 512, 0, stream>>>(emb_trg, trg, 49, WihT_d, dec_bih, dec_bhh, gih_dec, 1568);
    cast_bf16_kernel<<<4000, 256, 0, stream>>>(sm_w, smw_bf, 32000 * 128);

    // both recurrences concurrently (enc blocks 0..31, dec blocks 32..63)
    rnn_kernel<<<64, 512, 0, stream>>>(gih_enc, enc_Whh, gih_dec, dec_Whh, enc_out, hdec);

    // att_src = enc_out @ w1s^T + b1s
    tok_gemv_kernel<<<400, 128, 0, stream>>>(enc_out, nullptr, 0, w1sT, att_b1s, nullptr, att_src, 1600);

    // fully parallel attention + output projection
    att_par_kernel<<<dim3(49, 32), 128, 0, stream>>>(hdec, att_src, enc_out,
                                                     w1tT, att_b1t, att_w2, att_b2,
                                                     outwT, out_b, fin_bf);

    // big output GEMM (bf16 MFMA, fp32 accumulate)
    logits_gemm_kernel<<<dim3(250, 25), 256, 0, stream>>>(fin_bf, smw_bf, sm_b, out);
}